// Round 1
// baseline (207.488 us; speedup 1.0000x reference)
//
#include <hip/hip_runtime.h>

// NavierStokesLossMAC: B=8, H=W=1024
//   d_in[0] v_old (B,2,H,W) f32 | d_in[1] v_new (B,2,H,W) f32
//   d_in[2] p_new (B,1,H,W) f32 | d_in[3] mask  (B,1,H,W) i32
// out: (B,) f32
//
// R9: rolling-window blocks. R3-R8 evidence: time (~75us) invariant to HBM
// bytes, occupancy, and VMEM instr count -> not rate-limited; limited by
// (a) one-shot 4KB stream reads with no per-CU sequential locality
// (copy ubench: 6.3 TB/s sequential vs our 2.4 TB/s one-shot) and
// (b) compiler register-minimizing the 21-load burst into serialized
// latency batches (VGPR=60, ~600cyc/load per R7).
// Fix: block = full 1024-wide row, marches RY=8 rows down. 3-row register
// window; per row only 6 new vector loads (v rows y+2, p/mask row y+1),
// issued at iteration end, consumed one full compute body later (true SW
// pipeline). Streams advance sequentially 4KB/iter per block -> DRAM page
// locality. Grid 8*128=1024 = exactly 4 blocks/CU. Seam scalars (lane 0/63)
// prefetched in the same pipeline. ~120 VGPR expected under (256,3) cap.

#define NS_H 1024
#define NS_W 1024
#define RY   8                      // output rows per block
#define NBY  128                    // ceil(1022/8); last chunk does 6 rows
#define PARTS_PER_B NBY

__device__ __forceinline__ float4 ld4(const float* p) { return *(const float4*)p; }
__device__ __forceinline__ int4  ld4i(const int* p)   { return *(const int4*)p; }
__device__ __forceinline__ float4 avg4(float4 a, float4 b) {
    return make_float4(0.5f*(a.x+b.x), 0.5f*(a.y+b.y), 0.5f*(a.z+b.z), 0.5f*(a.w+b.w));
}
__device__ __forceinline__ float4 sub4(float4 a, float4 b) {
    return make_float4(a.x-b.x, a.y-b.y, a.z-b.z, a.w-b.w);
}

__global__ __launch_bounds__(256, 3) void ns_loss_partial(
    const float* __restrict__ v_old,
    const float* __restrict__ v_new,
    const float* __restrict__ p,
    const int*   __restrict__ mask,
    float* __restrict__ ws)
{
    const int blk = blockIdx.x;
    const int b   = blk / NBY;
    const int cy  = blk % NBY;
    const int y0  = 1 + cy * RY;
    const int ny  = min(RY, (NS_H - 1) - y0);   // 8, or 6 for last chunk

    const size_t hw = (size_t)NS_H * NS_W;
    const float* uo = v_old + (size_t)b * 2 * hw;
    const float* wo = uo + hw;
    const float* un = v_new + (size_t)b * 2 * hw;
    const float* wn = un + hw;
    const float* pb = p    + (size_t)b * hw;
    const int*   mb = mask + (size_t)b * hw;

    const int tid  = (int)threadIdx.x;
    const int lane = tid & 63;
    const int x0   = tid * 4;
    const bool seamL = (lane == 0)  && (x0 > 0);
    const bool seamR = (lane == 63) && (x0 + 4 < NS_W);

    // ---- prologue: rows y0-1, y0, y0+1 raw v; p rows y0-1,y0; mask y0 ----
    const int off_m = (y0 - 1) * NS_W + x0;
    const int off_c = off_m + NS_W;
    const int off_p = off_c + NS_W;
    const int off_q = off_p + NS_W;    // y0+2 <= 1019 always

    float4 t0 = ld4(un + off_m), t1 = ld4(uo + off_m);
    float4 t2 = ld4(wn + off_m), t3 = ld4(wo + off_m);
    float4 t4 = ld4(un + off_c), t5 = ld4(uo + off_c);
    float4 t6 = ld4(wn + off_c), t7 = ld4(wo + off_c);
    float4 t8 = ld4(un + off_p), t9 = ld4(uo + off_p);
    float4 ta = ld4(wn + off_p), tb = ld4(wo + off_p);
    float4 p_m4 = ld4(pb + off_m);
    float4 p_c4 = ld4(pb + off_c);
    int4   m_c4 = ld4i(mb + off_c);

    float4 u_m = avg4(t0, t1), w_m = avg4(t2, t3);
    float4 u_c = avg4(t4, t5), du_c = sub4(t4, t5);
    float4 w_c = avg4(t6, t7), dw_c = sub4(t6, t7);
    float4 u_p = avg4(t8, t9), du_p = sub4(t8, t9);
    float4 w_p = avg4(ta, tb), dw_p = sub4(ta, tb);

    // seam scalars for current row y0
    float s_ul = 0.f, s_wl = 0.f, s_pl = 0.f, s_ur = 0.f, s_wr = 0.f;
    if (seamL) {
        s_ul = 0.5f * (un[off_c - 1] + uo[off_c - 1]);
        s_wl = 0.5f * (wn[off_c - 1] + wo[off_c - 1]);
        s_pl = pb[off_c - 1];
    }
    if (seamR) {
        s_ur = 0.5f * (un[off_c + 4] + uo[off_c + 4]);
        s_wr = 0.5f * (wn[off_c + 4] + wo[off_c + 4]);
    }

    // in-flight prefetch: v row y0+2, p/mask row y0+1, seams row y0+1
    float4 f_un = ld4(un + off_q), f_uo = ld4(uo + off_q);
    float4 f_wn = ld4(wn + off_q), f_wo = ld4(wo + off_q);
    float4 f_p  = ld4(pb + off_p);
    int4   f_m  = ld4i(mb + off_p);
    float f_ul = 0.f, f_wl = 0.f, f_pl = 0.f, f_ur = 0.f, f_wr = 0.f;
    if (seamL) {
        f_ul = 0.5f * (un[off_p - 1] + uo[off_p - 1]);
        f_wl = 0.5f * (wn[off_p - 1] + wo[off_p - 1]);
        f_pl = pb[off_p - 1];
    }
    if (seamR) {
        f_ur = 0.5f * (un[off_p + 4] + uo[off_p + 4]);
        f_wr = 0.5f * (wn[off_p + 4] + wo[off_p + 4]);
    }

    float acc = 0.f;

    for (int r = 0; r < ny; ++r) {
        // ---- compute row y = y0 + r from register state ----
        float ul = __shfl_up(u_c.w, 1);   if (lane == 0)  ul = s_ul;
        float wl = __shfl_up(w_c.w, 1);   if (lane == 0)  wl = s_wl;
        float pl = __shfl_up(p_c4.w, 1);  if (lane == 0)  pl = s_pl;
        float ur = __shfl_down(u_c.x, 1); if (lane == 63) ur = s_ur;  // 0 at tid=255 (x=1023 masked)
        float wr = __shfl_down(w_c.x, 1); if (lane == 63) wr = s_wr;

        {
            const float uc[6]  = {ul, u_c.x, u_c.y, u_c.z, u_c.w, ur};
            const float wcv[6] = {wl, w_c.x, w_c.y, w_c.z, w_c.w, wr};
            const float uym[4] = {u_m.x, u_m.y, u_m.z, u_m.w};
            const float uyp[4] = {u_p.x, u_p.y, u_p.z, u_p.w};
            const float wym[4] = {w_m.x, w_m.y, w_m.z, w_m.w};
            const float wyp[4] = {w_p.x, w_p.y, w_p.z, w_p.w};
            const float du[4]  = {du_c.x, du_c.y, du_c.z, du_c.w};
            const float dw[4]  = {dw_c.x, dw_c.y, dw_c.z, dw_c.w};
            const float pcv[5] = {pl, p_c4.x, p_c4.y, p_c4.z, p_c4.w};
            const float pym[4] = {p_m4.x, p_m4.y, p_m4.z, p_m4.w};
            const int   mm[4]  = {m_c4.x, m_c4.y, m_c4.z, m_c4.w};

            #pragma unroll
            for (int j = 0; j < 4; ++j) {
                const int x = x0 + j;
                const float m = (x >= 1 && x <= NS_W - 2) ? (float)mm[j] : 0.f;
                const float u_cc = uc[j+1],  u_xm = uc[j],  u_xp = uc[j+2];
                const float w_cc = wcv[j+1], w_xm = wcv[j], w_xp = wcv[j+2];

                float res_x =
                    dw[j] * 0.25f
                  + w_cc * 0.5f * (w_xp - w_xm)
                  + 0.5f * ( 0.5f * (u_cc + u_xm) * (w_cc   - wym[j])
                           + 0.5f * (u_cc + u_xp) * (wyp[j] - w_cc  ) )
                  + (pcv[j+1] - pcv[j])
                  - 0.1f * (w_xm + w_xp + wym[j] + wyp[j] - 4.f * w_cc);

                float res_y =
                    du[j] * 0.25f
                  + u_cc * 0.5f * (uyp[j] - uym[j])
                  + 0.5f * ( 0.5f * (w_cc + wym[j]) * (u_cc - u_xm)
                           + 0.5f * (w_cc + wyp[j]) * (u_xp - u_cc) )
                  + (pcv[j+1] - pym[j])
                  - 0.1f * (u_xm + u_xp + uym[j] + uyp[j] - 4.f * u_cc);

                acc += m * (res_x * res_x + res_y * res_y);
            }
        }

        // ---- consume in-flight, rotate window ----
        u_m = u_c;  w_m = w_c;
        u_c = u_p;  w_c = w_p;  du_c = du_p;  dw_c = dw_p;
        u_p = avg4(f_un, f_uo); du_p = sub4(f_un, f_uo);
        w_p = avg4(f_wn, f_wo); dw_p = sub4(f_wn, f_wo);
        p_m4 = p_c4; p_c4 = f_p; m_c4 = f_m;
        s_ul = f_ul; s_wl = f_wl; s_pl = f_pl; s_ur = f_ur; s_wr = f_wr;

        // ---- issue next prefetch (flies across next iteration's compute) ----
        // v rows -> row y+3 (becomes u_p after next rotation); p/mask/seam -> row y+2
        int row_q = y0 + r + 3; if (row_q > NS_H - 1) row_q = NS_H - 1;  // clamp, wasted on last iter
        int row_n = y0 + r + 2; if (row_n > NS_H - 1) row_n = NS_H - 1;
        const int off_q2 = row_q * NS_W + x0;
        const int off_n  = row_n * NS_W + x0;
        f_un = ld4(un + off_q2); f_uo = ld4(uo + off_q2);
        f_wn = ld4(wn + off_q2); f_wo = ld4(wo + off_q2);
        f_p  = ld4(pb + off_n);
        f_m  = ld4i(mb + off_n);
        if (seamL) {
            f_ul = 0.5f * (un[off_n - 1] + uo[off_n - 1]);
            f_wl = 0.5f * (wn[off_n - 1] + wo[off_n - 1]);
            f_pl = pb[off_n - 1];
        }
        if (seamR) {
            f_ur = 0.5f * (un[off_n + 4] + uo[off_n + 4]);
            f_wr = 0.5f * (wn[off_n + 4] + wo[off_n + 4]);
        }
    }

    // ---- block reduction: wave shuffle -> 16B LDS -> one plain store ----
    #pragma unroll
    for (int off = 32; off > 0; off >>= 1)
        acc += __shfl_down(acc, off);

    __shared__ float smem[4];
    const int wid = tid >> 6;
    if (lane == 0) smem[wid] = acc;
    __syncthreads();

    if (tid == 0)
        ws[blk] = smem[0] + smem[1] + smem[2] + smem[3];
}

__global__ __launch_bounds__(256) void ns_loss_reduce(
    const float* __restrict__ ws, float* __restrict__ out)
{
    const int b = blockIdx.x;
    float acc = 0.f;
    for (int i = threadIdx.x; i < PARTS_PER_B; i += 256)
        acc += ws[b * PARTS_PER_B + i];

    #pragma unroll
    for (int off = 32; off > 0; off >>= 1)
        acc += __shfl_down(acc, off);

    __shared__ float smem[4];
    const int lane = threadIdx.x & 63;
    const int wid  = threadIdx.x >> 6;
    if (lane == 0) smem[wid] = acc;
    __syncthreads();

    if (threadIdx.x == 0) {
        const float inv = 1.0f / ((float)(NS_H - 2) * (float)(NS_W - 2));
        out[b] = (smem[0] + smem[1] + smem[2] + smem[3]) * inv;
    }
}

extern "C" void kernel_launch(void* const* d_in, const int* in_sizes, int n_in,
                              void* d_out, int out_size, void* d_ws, size_t ws_size,
                              hipStream_t stream) {
    const float* v_old = (const float*)d_in[0];
    const float* v_new = (const float*)d_in[1];
    const float* p_new = (const float*)d_in[2];
    const int*   msk   = (const int*)d_in[3];
    float* out = (float*)d_out;
    float* ws  = (float*)d_ws;

    const int B = out_size;   // 8

    ns_loss_partial<<<dim3(B * NBY), dim3(256), 0, stream>>>(v_old, v_new, p_new, msk, ws);
    ns_loss_reduce<<<dim3(B), dim3(256), 0, stream>>>(ws, out);
}

// Round 2
// 198.604 us; speedup vs baseline: 1.0447x; 1.0447x over previous
//
#include <hip/hip_runtime.h>

// NavierStokesLossMAC: B=8, H=W=1024
//   d_in[0] v_old (B,2,H,W) f32 | d_in[1] v_new (B,2,H,W) f32
//   d_in[2] p_new (B,1,H,W) f32 | d_in[3] mask  (B,1,H,W) i32
// out: (B,) f32
//
// R10: VMEM-instruction count is the binding resource (~70cyc/wave-instr/CU;
// time tracked instr count across R4/R8/R9 while bytes, occupancy, access
// pattern all varied; warm-L3 replays with FETCH~0 ran the same 85us ->
// not HBM-bound). Changes vs R9:
//  * ALL seam loads eliminated: seams are block-internal (x=0/1023 masked),
//    exchanged via 256B double-buffered LDS (DS pipe, not VMEM). -9
//    VMEM instrs/wave/row.
//  * TRUE 2-deep prefetch: two named in-flight register sets (A/B) consumed
//    on alternating unrolled iterations. R9's A<=B register copy forced the
//    waitcnt one iteration early (1-deep); naming both sets fixes it.
//  * 6 float4 loads/row/wave = compulsory minimum. ~75 VMEM instrs/wave
//    (307k total vs R8 638k / R9 594k).

#define NS_H 1024
#define NS_W 1024
#define RY   8                      // output rows per block
#define NBY  128                    // 127 full chunks + last chunk of 6 rows
#define PARTS_PER_B NBY

__device__ __forceinline__ float4 ld4(const float* p) { return *(const float4*)p; }
__device__ __forceinline__ int4  ld4i(const int* p)   { return *(const int4*)p; }
__device__ __forceinline__ float4 avg4(float4 a, float4 b) {
    return make_float4(0.5f*(a.x+b.x), 0.5f*(a.y+b.y), 0.5f*(a.z+b.z), 0.5f*(a.w+b.w));
}
__device__ __forceinline__ float4 sub4(float4 a, float4 b) {
    return make_float4(a.x-b.x, a.y-b.y, a.z-b.z, a.w-b.w);
}

__global__ __launch_bounds__(256, 3) void ns_loss_partial(
    const float* __restrict__ v_old,
    const float* __restrict__ v_new,
    const float* __restrict__ p,
    const int*   __restrict__ mask,
    float* __restrict__ ws)
{
    const int blk = blockIdx.x;
    const int b   = blk / NBY;
    const int cy  = blk % NBY;
    const int y0  = 1 + cy * RY;
    const int ny  = min(RY, (NS_H - 1) - y0);   // 8, or 6 for last chunk (always even)

    const size_t hw = (size_t)NS_H * NS_W;
    const float* uo = v_old + (size_t)b * 2 * hw;
    const float* wo = uo + hw;
    const float* un = v_new + (size_t)b * 2 * hw;
    const float* wn = un + hw;
    const float* pb = p    + (size_t)b * hw;
    const int*   mb = mask + (size_t)b * hw;

    const int tid  = (int)threadIdx.x;
    const int lane = tid & 63;
    const int wid  = tid >> 6;
    const int x0   = tid * 4;

    // seam exchange: [parity][wave][ {uL,wL,pL} from lane63, {uR,wR} from lane0 ]
    __shared__ float edge[2][4][8];

    // ---- prologue: base window rows y0-1, y0, y0+1 ----
    const int off_m = (y0 - 1) * NS_W + x0;
    const int off_c = off_m + NS_W;
    const int off_p = off_c + NS_W;

    float4 t0 = ld4(un + off_m), t1 = ld4(uo + off_m);
    float4 t2 = ld4(wn + off_m), t3 = ld4(wo + off_m);
    float4 t4 = ld4(un + off_c), t5 = ld4(uo + off_c);
    float4 t6 = ld4(wn + off_c), t7 = ld4(wo + off_c);
    float4 t8 = ld4(un + off_p), t9 = ld4(uo + off_p);
    float4 ta = ld4(wn + off_p), tb = ld4(wo + off_p);
    float4 p_m4 = ld4(pb + off_m);
    float4 p_c4 = ld4(pb + off_c);
    int4   m_c4 = ld4i(mb + off_c);

    // in-flight set A = S(y0):   v rows y0+2, p/mask row y0+1
    // in-flight set B = S(y0+1): v rows y0+3, p/mask row y0+2   (y0+3 <= 1020 always)
    const int offAv = (y0 + 2) * NS_W + x0, offAn = (y0 + 1) * NS_W + x0;
    const int offBv = (y0 + 3) * NS_W + x0, offBn = (y0 + 2) * NS_W + x0;
    float4 a_un = ld4(un + offAv), a_uo = ld4(uo + offAv);
    float4 a_wn = ld4(wn + offAv), a_wo = ld4(wo + offAv);
    float4 a_p  = ld4(pb + offAn); int4 a_m = ld4i(mb + offAn);
    float4 b_un = ld4(un + offBv), b_uo = ld4(uo + offBv);
    float4 b_wn = ld4(wn + offBv), b_wo = ld4(wo + offBv);
    float4 b_p  = ld4(pb + offBn); int4 b_m = ld4i(mb + offBn);

    float4 u_m = avg4(t0, t1), w_m = avg4(t2, t3);
    float4 u_c = avg4(t4, t5), du_c = sub4(t4, t5);
    float4 w_c = avg4(t6, t7), dw_c = sub4(t6, t7);
    float4 u_p = avg4(t8, t9), du_p = sub4(t8, t9);
    float4 w_p = avg4(ta, tb), dw_p = sub4(ta, tb);

    float acc = 0.f;

    auto iter = [&](int r, float4& g_un, float4& g_uo, float4& g_wn, float4& g_wo,
                    float4& g_p, int4& g_m) {
        const int y   = y0 + r;
        const int par = r & 1;

        // publish this row's block-internal seam values (DS pipe, no VMEM)
        if (lane == 63) {
            edge[par][wid][0] = u_c.w; edge[par][wid][1] = w_c.w; edge[par][wid][2] = p_c4.w;
        }
        if (lane == 0) {
            edge[par][wid][3] = u_c.x; edge[par][wid][4] = w_c.x;
        }
        __syncthreads();

        float ul = __shfl_up(u_c.w, 1), wl = __shfl_up(w_c.w, 1), pl = __shfl_up(p_c4.w, 1);
        if (lane == 0 && wid > 0) {
            ul = edge[par][wid-1][0]; wl = edge[par][wid-1][1]; pl = edge[par][wid-1][2];
        }
        float ur = __shfl_down(u_c.x, 1), wr = __shfl_down(w_c.x, 1);
        if (lane == 63 && wid < 3) {
            ur = edge[par][wid+1][3]; wr = edge[par][wid+1][4];
        }
        // (x=0 / x=1023 seams keep the shuffle's own finite value; masked anyway)

        {
            const float uc[6]  = {ul, u_c.x, u_c.y, u_c.z, u_c.w, ur};
            const float wcv[6] = {wl, w_c.x, w_c.y, w_c.z, w_c.w, wr};
            const float uym[4] = {u_m.x, u_m.y, u_m.z, u_m.w};
            const float uyp[4] = {u_p.x, u_p.y, u_p.z, u_p.w};
            const float wym[4] = {w_m.x, w_m.y, w_m.z, w_m.w};
            const float wyp[4] = {w_p.x, w_p.y, w_p.z, w_p.w};
            const float du[4]  = {du_c.x, du_c.y, du_c.z, du_c.w};
            const float dw[4]  = {dw_c.x, dw_c.y, dw_c.z, dw_c.w};
            const float pcv[5] = {pl, p_c4.x, p_c4.y, p_c4.z, p_c4.w};
            const float pym[4] = {p_m4.x, p_m4.y, p_m4.z, p_m4.w};
            const int   mm[4]  = {m_c4.x, m_c4.y, m_c4.z, m_c4.w};

            #pragma unroll
            for (int j = 0; j < 4; ++j) {
                const int x = x0 + j;
                const float m = (x >= 1 && x <= NS_W - 2) ? (float)mm[j] : 0.f;
                const float u_cc = uc[j+1],  u_xm = uc[j],  u_xp = uc[j+2];
                const float w_cc = wcv[j+1], w_xm = wcv[j], w_xp = wcv[j+2];

                float res_x =
                    dw[j] * 0.25f
                  + w_cc * 0.5f * (w_xp - w_xm)
                  + 0.5f * ( 0.5f * (u_cc + u_xm) * (w_cc   - wym[j])
                           + 0.5f * (u_cc + u_xp) * (wyp[j] - w_cc  ) )
                  + (pcv[j+1] - pcv[j])
                  - 0.1f * (w_xm + w_xp + wym[j] + wyp[j] - 4.f * w_cc);

                float res_y =
                    du[j] * 0.25f
                  + u_cc * 0.5f * (uyp[j] - uym[j])
                  + 0.5f * ( 0.5f * (w_cc + wym[j]) * (u_cc - u_xm)
                           + 0.5f * (w_cc + wyp[j]) * (u_xp - u_cc) )
                  + (pcv[j+1] - pym[j])
                  - 0.1f * (u_xm + u_xp + uym[j] + uyp[j] - 4.f * u_cc);

                acc += m * (res_x * res_x + res_y * res_y);
            }
        }

        // rotate window, consuming this iteration's in-flight set
        u_m = u_c;  w_m = w_c;
        u_c = u_p;  w_c = w_p;  du_c = du_p;  dw_c = dw_p;
        u_p = avg4(g_un, g_uo); du_p = sub4(g_un, g_uo);
        w_p = avg4(g_wn, g_wo); dw_p = sub4(g_wn, g_wo);
        p_m4 = p_c4; p_c4 = g_p; m_c4 = g_m;

        // reissue same set = S(y+2): v rows y+4, p/mask row y+3 (clamped; consumed at r+2)
        int rv = y + 4; if (rv > NS_H - 1) rv = NS_H - 1;
        int rn = y + 3; if (rn > NS_H - 1) rn = NS_H - 1;
        const int ov = rv * NS_W + x0;
        const int on = rn * NS_W + x0;
        g_un = ld4(un + ov); g_uo = ld4(uo + ov);
        g_wn = ld4(wn + ov); g_wo = ld4(wo + ov);
        g_p  = ld4(pb + on); g_m  = ld4i(mb + on);
    };

    for (int r = 0; r + 1 < ny; r += 2) {
        iter(r,     a_un, a_uo, a_wn, a_wo, a_p, a_m);
        iter(r + 1, b_un, b_uo, b_wn, b_wo, b_p, b_m);
    }

    // ---- block reduction: wave shuffle -> 16B LDS -> one plain store ----
    #pragma unroll
    for (int off = 32; off > 0; off >>= 1)
        acc += __shfl_down(acc, off);

    __shared__ float smem[4];
    if (lane == 0) smem[wid] = acc;
    __syncthreads();

    if (tid == 0)
        ws[blk] = smem[0] + smem[1] + smem[2] + smem[3];
}

__global__ __launch_bounds__(256) void ns_loss_reduce(
    const float* __restrict__ ws, float* __restrict__ out)
{
    const int b = blockIdx.x;
    float acc = 0.f;
    for (int i = threadIdx.x; i < PARTS_PER_B; i += 256)
        acc += ws[b * PARTS_PER_B + i];

    #pragma unroll
    for (int off = 32; off > 0; off >>= 1)
        acc += __shfl_down(acc, off);

    __shared__ float smem[4];
    const int lane = threadIdx.x & 63;
    const int wid  = threadIdx.x >> 6;
    if (lane == 0) smem[wid] = acc;
    __syncthreads();

    if (threadIdx.x == 0) {
        const float inv = 1.0f / ((float)(NS_H - 2) * (float)(NS_W - 2));
        out[b] = (smem[0] + smem[1] + smem[2] + smem[3]) * inv;
    }
}

extern "C" void kernel_launch(void* const* d_in, const int* in_sizes, int n_in,
                              void* d_out, int out_size, void* d_ws, size_t ws_size,
                              hipStream_t stream) {
    const float* v_old = (const float*)d_in[0];
    const float* v_new = (const float*)d_in[1];
    const float* p_new = (const float*)d_in[2];
    const int*   msk   = (const int*)d_in[3];
    float* out = (float*)d_out;
    float* ws  = (float*)d_ws;

    const int B = out_size;   // 8

    ns_loss_partial<<<dim3(B * NBY), dim3(256), 0, stream>>>(v_old, v_new, p_new, msk, ws);
    ns_loss_reduce<<<dim3(B), dim3(256), 0, stream>>>(ws, out);
}